// Round 3
// baseline (80.139 us; speedup 1.0000x reference)
//
#include <hip/hip_runtime.h>
#include <stdint.h>

#define N_RAY 131072
#define NS 128
#define BIG_DELTA 1e10f
#define EPS 1e-10f
#define RAYS_PB 8   // rays per block = rays per wave (1 wave/block)

// async global->LDS, 16B per lane; LDS dest = uniform base + lane*16
__device__ __forceinline__ void gload16(const void* g, void* l) {
    __builtin_amdgcn_global_load_lds(
        (const __attribute__((address_space(1))) void*)g,
        (__attribute__((address_space(3))) void*)l, 16, 0, 0);
}

// Layout: one wave (64 lanes) per block handles 8 rays.
// Compute mapping: rc = lane>>3 (ray in block), u = lane&7 (16-sample chunk).
// LDS tiles are transposed [quad q][ray r] so compute-side ds_read_b128 puts
// each ray group on its own bank-quad (conflict-free), while the staging
// instructions read contiguous 128B runs per ray (16 full lines / instr).
__global__ __launch_bounds__(64) void volrender_kernel(
    const float4* __restrict__ rgb4,    // N_RAY * 96 float4
    const float4* __restrict__ sigma4,  // N_RAY * 32 float4
    const float4* __restrict__ z4,      // N_RAY * 32 float4
    const int* __restrict__ wb_flag,
    float* __restrict__ out)
{
    __shared__ float4 zt[32 * 8];   // [q][r]
    __shared__ float4 st[32 * 8];
    __shared__ float4 ct[96 * 8];

    const int lane = threadIdx.x;       // 0..63
    const int rayBase = blockIdx.x * RAYS_PB;

    // staging decomposition: LDS slot s = k*64 + lane -> q = k*8 + (lane>>3), r = lane&7
    const int sr = lane & 7;
    const int sh = lane >> 3;

    const size_t zb = (size_t)rayBase * 32;
    #pragma unroll
    for (int k = 0; k < 4; ++k)
        gload16(&z4[zb + (size_t)sr * 32 + (k * 8 + sh)], &zt[k * 64]);
    #pragma unroll
    for (int k = 0; k < 4; ++k)
        gload16(&sigma4[zb + (size_t)sr * 32 + (k * 8 + sh)], &st[k * 64]);
    const size_t cbase = (size_t)rayBase * 96;
    #pragma unroll
    for (int k = 0; k < 12; ++k)
        gload16(&rgb4[cbase + (size_t)sr * 96 + (k * 8 + sh)], &ct[k * 64]);

    asm volatile("s_waitcnt vmcnt(0)" ::: "memory");
    __syncthreads();

    // ---- compute mapping
    const int rc = lane >> 3;   // ray within block
    const int u  = lane & 7;    // chunk index: samples 16u .. 16u+15

    float zz[17], ss[16];
    #pragma unroll
    for (int k = 0; k < 4; ++k) {
        float4 v = zt[(4 * u + k) * 8 + rc];
        zz[4 * k + 0] = v.x; zz[4 * k + 1] = v.y;
        zz[4 * k + 2] = v.z; zz[4 * k + 3] = v.w;
        float4 s = st[(4 * u + k) * 8 + rc];
        ss[4 * k + 0] = s.x; ss[4 * k + 1] = s.y;
        ss[4 * k + 2] = s.z; ss[4 * k + 3] = s.w;
    }
    // first z of next chunk (unused for u==7; clamped slot stays in-bounds)
    zz[16] = zt[((u < 7) ? (4 * u + 4) : 31) * 8 + rc].x;

    float a[16], t[16];
    #pragma unroll
    for (int j = 0; j < 16; ++j) {
        float dd = (j == 15) ? ((u == 7) ? BIG_DELTA : (zz[16] - zz[15]))
                             : (zz[j + 1] - zz[j]);
        float sg = fmaxf(ss[j], 0.0f);
        a[j] = 1.0f - __expf(-dd * sg);
        t[j] = 1.0f - a[j] + EPS;
    }

    // product of this lane's 16 transmittance terms (tree)
    float p01, p23, p45, p67;
    p01 = (t[0] * t[1]) * (t[2] * t[3]);
    p23 = (t[4] * t[5]) * (t[6] * t[7]);
    p45 = (t[8] * t[9]) * (t[10] * t[11]);
    p67 = (t[12] * t[13]) * (t[14] * t[15]);
    float p = (p01 * p23) * (p45 * p67);

    // inclusive scan over the 8-lane ray group (width-8 -> DPP row ops)
    float sc = p;
    #pragma unroll
    for (int d = 1; d < 8; d <<= 1) {
        float qv = __shfl_up(sc, d, 8);
        if (u >= d) sc *= qv;
    }
    // exclusive prefix for this lane's first sample
    float e = __shfl_up(sc, 1, 8);
    if (u == 0) e = 1.0f;

    // weights + depth/opacity partials
    float w[16];
    float E = e, dep = 0.0f, op = 0.0f;
    #pragma unroll
    for (int j = 0; j < 16; ++j) {
        w[j] = a[j] * E;
        E *= t[j];
        dep += w[j] * zz[j];
        op  += w[j];
    }

    // store weights (4 x float4 per lane; 64B-stride, L2 write-combines)
    {
        float4* wq = reinterpret_cast<float4*>(out + (size_t)N_RAY * 5);
        size_t wbase = ((size_t)(rayBase + rc)) * 32 + 4 * u;
        #pragma unroll
        for (int k = 0; k < 4; ++k)
            wq[wbase + k] = make_float4(w[4 * k], w[4 * k + 1], w[4 * k + 2], w[4 * k + 3]);
    }

    // rgb accumulation: lane's 48 floats = samples 16u..16u+15, channels aligned
    float cr = 0.0f, cg = 0.0f, cb = 0.0f;
    #pragma unroll
    for (int j = 0; j < 12; ++j) {
        float4 c = ct[(12 * u + j) * 8 + rc];
        const int f = 4 * j;          // local float index (compile-time)
        const int s0 = f / 3;
        if ((f % 3) == 0) {           // ch 0,1,2,0 ; samples s0,s0,s0,s0+1
            cr += c.x * w[s0]; cg += c.y * w[s0];
            cb += c.z * w[s0]; cr += c.w * w[s0 + 1];
        } else if ((f % 3) == 1) {    // ch 1,2,0,1 ; samples s0,s0,s0+1,s0+1
            cg += c.x * w[s0]; cb += c.y * w[s0];
            cr += c.z * w[s0 + 1]; cg += c.w * w[s0 + 1];
        } else {                      // ch 2,0,1,2 ; samples s0,s0+1,s0+1,s0+1
            cb += c.x * w[s0]; cr += c.y * w[s0 + 1];
            cg += c.z * w[s0 + 1]; cb += c.w * w[s0 + 1];
        }
    }

    // width-8 reductions (DPP row_shr)
    #pragma unroll
    for (int d = 4; d >= 1; d >>= 1) {
        cr  += __shfl_down(cr,  d, 8);
        cg  += __shfl_down(cg,  d, 8);
        cb  += __shfl_down(cb,  d, 8);
        dep += __shfl_down(dep, d, 8);
        op  += __shfl_down(op,  d, 8);
    }

    if (u == 0) {
        const int ray = rayBase + rc;
        const float add = (*wb_flag) ? (1.0f - op) : 0.0f;
        out[(size_t)ray * 3 + 0] = cr + add;
        out[(size_t)ray * 3 + 1] = cg + add;
        out[(size_t)ray * 3 + 2] = cb + add;
        out[(size_t)N_RAY * 3 + ray] = dep;
        out[(size_t)N_RAY * 4 + ray] = op;
    }
}

extern "C" void kernel_launch(void* const* d_in, const int* in_sizes, int n_in,
                              void* d_out, int out_size, void* d_ws, size_t ws_size,
                              hipStream_t stream) {
    const float4* rgb    = (const float4*)d_in[0];
    const float4* sigma  = (const float4*)d_in[1];
    const float4* z_vals = (const float4*)d_in[2];
    const int*    wb     = (const int*)d_in[3];
    float* out = (float*)d_out;

    const int blocks = N_RAY / RAYS_PB;   // 16384 blocks x 64 threads
    volrender_kernel<<<blocks, 64, 0, stream>>>(rgb, sigma, z_vals, wb, out);
}

// Round 4
// 80.047 us; speedup vs baseline: 1.0012x; 1.0012x over previous
//
#include <hip/hip_runtime.h>

#define N_RAY 131072
#define NS 128
#define BIG_DELTA 1e10f
#define EPS 1e-10f

// DPP move with explicit identity for invalid/masked lanes (bound_ctrl=false).
#define DPPF(OLD, V, CTRL, RM) \
  __int_as_float(__builtin_amdgcn_update_dpp(__float_as_int(OLD), __float_as_int(V), (CTRL), (RM), 0xf, false))

// DPP ctrl encodings (gfx9/CDNA): row_shr:N = 0x110+N, wave_shl:1 = 0x130,
// wave_shr:1 = 0x138, row_bcast:15 = 0x142, row_bcast:31 = 0x143.

// Inclusive multiply-scan over 64 lanes (identity = 1.0).
__device__ __forceinline__ float mul_scan_incl(float p) {
    p *= DPPF(1.0f, p, 0x111, 0xf);
    p *= DPPF(1.0f, p, 0x112, 0xf);
    p *= DPPF(1.0f, p, 0x114, 0xf);
    p *= DPPF(1.0f, p, 0x118, 0xf);
    p *= DPPF(1.0f, p, 0x142, 0xa);   // rows 1,3 += lane15/47
    p *= DPPF(1.0f, p, 0x143, 0xc);   // rows 2,3 += lane31
    return p;
}

// Sum over 64 lanes -> uniform scalar (scan pattern, total lands in lane 63).
__device__ __forceinline__ float wave_sum(float v) {
    v += DPPF(0.0f, v, 0x111, 0xf);
    v += DPPF(0.0f, v, 0x112, 0xf);
    v += DPPF(0.0f, v, 0x114, 0xf);
    v += DPPF(0.0f, v, 0x118, 0xf);
    v += DPPF(0.0f, v, 0x142, 0xa);
    v += DPPF(0.0f, v, 0x143, 0xc);
    return __int_as_float(__builtin_amdgcn_readlane(__float_as_int(v), 63));
}

// One wave = 4 rays (sequential), 2 samples/lane, all loads staged up-front.
__global__ __launch_bounds__(256) void volrender_kernel(
    const float* __restrict__ rgb,
    const float* __restrict__ sigma,
    const float* __restrict__ z_vals,
    const int* __restrict__ wb_flag,
    float* __restrict__ out)
{
    const int lane = threadIdx.x & 63;
    const int wid  = (blockIdx.x * blockDim.x + threadIdx.x) >> 6;  // global wave
    const size_t ray0 = (size_t)wid * 4;

    // ---- stage all loads (max MLP; fully coalesced float2)
    float2 zv[4], sv[4], c01[4], c23[4], c45[4];
    #pragma unroll
    for (int k = 0; k < 4; ++k) {
        const size_t base = (ray0 + k) * NS + 2 * lane;
        zv[k] = *reinterpret_cast<const float2*>(&z_vals[base]);
        sv[k] = *reinterpret_cast<const float2*>(&sigma[base]);
        const float* rp = rgb + (ray0 + k) * (NS * 3) + 6 * lane;
        c01[k] = *reinterpret_cast<const float2*>(rp);
        c23[k] = *reinterpret_cast<const float2*>(rp + 2);
        c45[k] = *reinterpret_cast<const float2*>(rp + 4);
    }

    float crs[4], cgs[4], cbs[4], dps[4], ops[4];
    float* wout = out + (size_t)N_RAY * 5;

    #pragma unroll
    for (int k = 0; k < 4; ++k) {
        const float2 z = zv[k];
        const float2 s = sv[k];

        // z[2l+2] from lane l+1 (wave_shl:1); lane 63 overridden below
        float znext = DPPF(0.0f, z.x, 0x130, 0xf);
        float d0 = z.y - z.x;
        float d1 = (lane == 63) ? BIG_DELTA : (znext - z.y);

        float e0 = __expf(-d0 * fmaxf(s.x, 0.0f));
        float e1 = __expf(-d1 * fmaxf(s.y, 0.0f));
        float a0 = 1.0f - e0, a1 = 1.0f - e1;
        float t0 = e0 + EPS,  t1 = e1 + EPS;   // == 1 - alpha + EPS

        // exclusive cumprod across the wave
        float p = mul_scan_incl(t0 * t1);
        float E = DPPF(1.0f, p, 0x138, 0xf);   // wave_shr:1; lane0 = 1.0

        float w0 = a0 * E;
        float w1 = a1 * (E * t0);

        // weights out
        *reinterpret_cast<float2*>(&wout[(ray0 + k) * NS + 2 * lane]) =
            make_float2(w0, w1);

        // partials: s0 rgb=(c01.x,c01.y,c23.x), s1 rgb=(c23.y,c45.x,c45.y)
        float r   = w0 * c01[k].x + w1 * c23[k].y;
        float g   = w0 * c01[k].y + w1 * c45[k].x;
        float b   = w0 * c23[k].x + w1 * c45[k].y;
        float dep = w0 * z.x      + w1 * z.y;
        float op  = w0 + w1;

        crs[k] = wave_sum(r);
        cgs[k] = wave_sum(g);
        cbs[k] = wave_sum(b);
        dps[k] = wave_sum(dep);
        ops[k] = wave_sum(op);
    }

    if (lane == 0) {
        const int wb = *wb_flag;
        float ad[4];
        #pragma unroll
        for (int k = 0; k < 4; ++k) ad[k] = wb ? (1.0f - ops[k]) : 0.0f;

        // comp_rgb: 12 consecutive floats at out[12*wid]
        float4* co = reinterpret_cast<float4*>(out + (size_t)wid * 12);
        co[0] = make_float4(crs[0] + ad[0], cgs[0] + ad[0], cbs[0] + ad[0], crs[1] + ad[1]);
        co[1] = make_float4(cgs[1] + ad[1], cbs[1] + ad[1], crs[2] + ad[2], cgs[2] + ad[2]);
        co[2] = make_float4(cbs[2] + ad[2], crs[3] + ad[3], cgs[3] + ad[3], cbs[3] + ad[3]);

        reinterpret_cast<float4*>(out + (size_t)N_RAY * 3)[wid] =
            make_float4(dps[0], dps[1], dps[2], dps[3]);
        reinterpret_cast<float4*>(out + (size_t)N_RAY * 4)[wid] =
            make_float4(ops[0], ops[1], ops[2], ops[3]);
    }
}

extern "C" void kernel_launch(void* const* d_in, const int* in_sizes, int n_in,
                              void* d_out, int out_size, void* d_ws, size_t ws_size,
                              hipStream_t stream) {
    const float* rgb    = (const float*)d_in[0];
    const float* sigma  = (const float*)d_in[1];
    const float* z_vals = (const float*)d_in[2];
    const int*   wb     = (const int*)d_in[3];
    float* out = (float*)d_out;

    // 4 waves/block, 4 rays/wave -> 16 rays/block
    const int blocks = N_RAY / 16;   // 8192
    volrender_kernel<<<blocks, 256, 0, stream>>>(rgb, sigma, z_vals, wb, out);
}

// Round 5
// 79.973 us; speedup vs baseline: 1.0021x; 1.0009x over previous
//
#include <hip/hip_runtime.h>

#define N_RAY 131072
#define NS 128
#define BIG_DELTA 1e10f
#define EPS 1e-10f

// DPP move with explicit identity for invalid/masked lanes (bound_ctrl=false).
#define DPPF(OLD, V, CTRL, RM) \
  __int_as_float(__builtin_amdgcn_update_dpp(__float_as_int(OLD), __float_as_int(V), (CTRL), (RM), 0xf, false))

// DPP ctrl encodings (gfx9/CDNA): row_shr:N = 0x110+N, wave_shl:1 = 0x130,
// wave_shr:1 = 0x138, row_bcast:15 = 0x142, row_bcast:31 = 0x143.

// Inclusive multiply-scan over 64 lanes (identity = 1.0).
__device__ __forceinline__ float mul_scan_incl(float p) {
    p *= DPPF(1.0f, p, 0x111, 0xf);
    p *= DPPF(1.0f, p, 0x112, 0xf);
    p *= DPPF(1.0f, p, 0x114, 0xf);
    p *= DPPF(1.0f, p, 0x118, 0xf);
    p *= DPPF(1.0f, p, 0x142, 0xa);   // rows 1,3 += lane15/47
    p *= DPPF(1.0f, p, 0x143, 0xc);   // rows 2,3 += lane31
    return p;
}

// Sum over 64 lanes -> uniform scalar (scan pattern, total lands in lane 63).
__device__ __forceinline__ float wave_sum(float v) {
    v += DPPF(0.0f, v, 0x111, 0xf);
    v += DPPF(0.0f, v, 0x112, 0xf);
    v += DPPF(0.0f, v, 0x114, 0xf);
    v += DPPF(0.0f, v, 0x118, 0xf);
    v += DPPF(0.0f, v, 0x142, 0xa);
    v += DPPF(0.0f, v, 0x143, 0xc);
    return __int_as_float(__builtin_amdgcn_readlane(__float_as_int(v), 63));
}

// One wave = 4 rays (sequential), 2 samples/lane, all loads staged up-front.
__global__ __launch_bounds__(256) void volrender_kernel(
    const float* __restrict__ rgb,
    const float* __restrict__ sigma,
    const float* __restrict__ z_vals,
    const int* __restrict__ wb_flag,
    float* __restrict__ out)
{
    const int lane = threadIdx.x & 63;
    const int wid  = (blockIdx.x * blockDim.x + threadIdx.x) >> 6;  // global wave
    const size_t ray0 = (size_t)wid * 4;

    // ---- stage all loads (max MLP; fully coalesced float2)
    float2 zv[4], sv[4], c01[4], c23[4], c45[4];
    #pragma unroll
    for (int k = 0; k < 4; ++k) {
        const size_t base = (ray0 + k) * NS + 2 * lane;
        zv[k] = *reinterpret_cast<const float2*>(&z_vals[base]);
        sv[k] = *reinterpret_cast<const float2*>(&sigma[base]);
        const float* rp = rgb + (ray0 + k) * (NS * 3) + 6 * lane;
        c01[k] = *reinterpret_cast<const float2*>(rp);
        c23[k] = *reinterpret_cast<const float2*>(rp + 2);
        c45[k] = *reinterpret_cast<const float2*>(rp + 4);
    }

    float crs[4], cgs[4], cbs[4], dps[4], ops[4];
    float* wout = out + (size_t)N_RAY * 5;

    #pragma unroll
    for (int k = 0; k < 4; ++k) {
        const float2 z = zv[k];
        const float2 s = sv[k];

        // z[2l+2] from lane l+1 (wave_shl:1); lane 63 overridden below
        float znext = DPPF(0.0f, z.x, 0x130, 0xf);
        float d0 = z.y - z.x;
        float d1 = (lane == 63) ? BIG_DELTA : (znext - z.y);

        float e0 = __expf(-d0 * fmaxf(s.x, 0.0f));
        float e1 = __expf(-d1 * fmaxf(s.y, 0.0f));
        float a0 = 1.0f - e0, a1 = 1.0f - e1;
        float t0 = e0 + EPS,  t1 = e1 + EPS;   // == 1 - alpha + EPS

        // exclusive cumprod across the wave
        float p = mul_scan_incl(t0 * t1);
        float E = DPPF(1.0f, p, 0x138, 0xf);   // wave_shr:1; lane0 = 1.0

        float w0 = a0 * E;
        float w1 = a1 * (E * t0);

        // weights out
        *reinterpret_cast<float2*>(&wout[(ray0 + k) * NS + 2 * lane]) =
            make_float2(w0, w1);

        // partials: s0 rgb=(c01.x,c01.y,c23.x), s1 rgb=(c23.y,c45.x,c45.y)
        float r   = w0 * c01[k].x + w1 * c23[k].y;
        float g   = w0 * c01[k].y + w1 * c45[k].x;
        float b   = w0 * c23[k].x + w1 * c45[k].y;
        float dep = w0 * z.x      + w1 * z.y;
        float op  = w0 + w1;

        crs[k] = wave_sum(r);
        cgs[k] = wave_sum(g);
        cbs[k] = wave_sum(b);
        dps[k] = wave_sum(dep);
        ops[k] = wave_sum(op);
    }

    if (lane == 0) {
        const int wb = *wb_flag;
        float ad[4];
        #pragma unroll
        for (int k = 0; k < 4; ++k) ad[k] = wb ? (1.0f - ops[k]) : 0.0f;

        // comp_rgb: 12 consecutive floats at out[12*wid]
        float4* co = reinterpret_cast<float4*>(out + (size_t)wid * 12);
        co[0] = make_float4(crs[0] + ad[0], cgs[0] + ad[0], cbs[0] + ad[0], crs[1] + ad[1]);
        co[1] = make_float4(cgs[1] + ad[1], cbs[1] + ad[1], crs[2] + ad[2], cgs[2] + ad[2]);
        co[2] = make_float4(cbs[2] + ad[2], crs[3] + ad[3], cgs[3] + ad[3], cbs[3] + ad[3]);

        reinterpret_cast<float4*>(out + (size_t)N_RAY * 3)[wid] =
            make_float4(dps[0], dps[1], dps[2], dps[3]);
        reinterpret_cast<float4*>(out + (size_t)N_RAY * 4)[wid] =
            make_float4(ops[0], ops[1], ops[2], ops[3]);
    }
}

extern "C" void kernel_launch(void* const* d_in, const int* in_sizes, int n_in,
                              void* d_out, int out_size, void* d_ws, size_t ws_size,
                              hipStream_t stream) {
    const float* rgb    = (const float*)d_in[0];
    const float* sigma  = (const float*)d_in[1];
    const float* z_vals = (const float*)d_in[2];
    const int*   wb     = (const int*)d_in[3];
    float* out = (float*)d_out;

    // 4 waves/block, 4 rays/wave -> 16 rays/block
    const int blocks = N_RAY / 16;   // 8192
    volrender_kernel<<<blocks, 256, 0, stream>>>(rgb, sigma, z_vals, wb, out);
}